// Round 1
// baseline (1277.404 us; speedup 1.0000x reference)
//
#include <hip/hip_runtime.h>

constexpr int IN_DIM  = 256;
constexpr int HID_DIM = 128;
constexpr int OUT_DIM = 64;

// ---------------- degree / CSR build ----------------

__global__ __launch_bounds__(256) void k_zero(int* __restrict__ p, int n) {
  int i = blockIdx.x * 256 + threadIdx.x;
  if (i < n) p[i] = 0;
}

__global__ __launch_bounds__(256) void k_count(const int* __restrict__ dst, int E,
                                               int* __restrict__ cnt) {
  int e = blockIdx.x * 256 + threadIdx.x;
  if (e < E) atomicAdd(&cnt[dst[e]], 1);
}

// per-1024-element block sums
__global__ __launch_bounds__(256) void k_bsum(const int* __restrict__ cnt, int n,
                                              int* __restrict__ bsum) {
  __shared__ int sh[256];
  int t = threadIdx.x;
  int i0 = blockIdx.x * 1024 + t * 4;
  int s = 0;
#pragma unroll
  for (int j = 0; j < 4; j++) { int i = i0 + j; if (i < n) s += cnt[i]; }
  sh[t] = s; __syncthreads();
  for (int off = 128; off > 0; off >>= 1) {
    if (t < off) sh[t] += sh[t + off];
    __syncthreads();
  }
  if (t == 0) bsum[blockIdx.x] = sh[0];
}

// exclusive scan of block sums (nb <= 256), single block
__global__ void k_bscan(int* __restrict__ bsum, int nb) {
  __shared__ int sh[256];
  int t = threadIdx.x;
  if (t < nb) sh[t] = bsum[t];
  __syncthreads();
  if (t == 0) {
    int run = 0;
    for (int i = 0; i < nb; i++) { int v = sh[i]; sh[i] = run; run += v; }
  }
  __syncthreads();
  if (t < nb) bsum[t] = sh[t];
}

// final: rowptr (exclusive scan), cursor copy, dis = rsqrt(deg+1)
__global__ __launch_bounds__(256) void k_scan_final(
    const int* __restrict__ cnt, int n, const int* __restrict__ bbase,
    int* __restrict__ rowptr, int* __restrict__ pos, float* __restrict__ dis, int E) {
  __shared__ int sh[256];
  int t = threadIdx.x;
  int i0 = blockIdx.x * 1024 + t * 4;
  int c[4]; int s = 0;
#pragma unroll
  for (int j = 0; j < 4; j++) { int i = i0 + j; c[j] = (i < n) ? cnt[i] : 0; s += c[j]; }
  sh[t] = s; __syncthreads();
  for (int off = 1; off < 256; off <<= 1) {
    int add = (t >= off) ? sh[t - off] : 0;
    __syncthreads();
    sh[t] += add;
    __syncthreads();
  }
  int run = bbase[blockIdx.x] + sh[t] - s;  // exclusive prefix for this thread
#pragma unroll
  for (int j = 0; j < 4; j++) {
    int i = i0 + j;
    if (i < n) {
      rowptr[i] = run;
      pos[i] = run;
      dis[i] = rsqrtf((float)c[j] + 1.0f);  // +1 self loop
      run += c[j];
    }
  }
  if (blockIdx.x == 0 && t == 0) rowptr[n] = E;
}

__global__ __launch_bounds__(256) void k_fill(const int* __restrict__ src,
                                              const int* __restrict__ dst, int E,
                                              int* __restrict__ pos, int* __restrict__ col) {
  int e = blockIdx.x * 256 + threadIdx.x;
  if (e < E) {
    int d = dst[e];
    int p = atomicAdd(&pos[d], 1);
    col[p] = src[e];
  }
}

// ---------------- GEMM: out[r][c] = dis[r] * sum_k A[r][k]*W[k][c] ----------------
// BM=64, BK=32, block=256 (16 col-threads x 16 row-threads, 4 rows x N/16 cols each)

template <int K, int N>
__global__ __launch_bounds__(256) void k_gemm(const float* __restrict__ A,
                                              const float* __restrict__ W,
                                              const float* __restrict__ dis,
                                              float* __restrict__ out, int M) {
  constexpr int CPT = N / 16;  // cols per thread: 8 (N=128) or 4 (N=64)
  __shared__ float Xs[64][33];  // +1 pad: conflict-free column reads
  __shared__ float Ws[32][N];
  const int tid = threadIdx.x;
  const int tx = tid & 15;
  const int ty = tid >> 4;
  const int row0 = blockIdx.x * 64;
  float acc[4][CPT];
#pragma unroll
  for (int i = 0; i < 4; i++)
#pragma unroll
    for (int j = 0; j < CPT; j++) acc[i][j] = 0.f;

  for (int k0 = 0; k0 < K; k0 += 32) {
    __syncthreads();
    // stage X tile: 64x32 floats (512 float4 / 256 threads = 2 each)
#pragma unroll
    for (int idx = tid; idx < 512; idx += 256) {
      int fi = idx * 4; int r = fi >> 5; int f = fi & 31;
      int gr = row0 + r; if (gr > M - 1) gr = M - 1;
      const float4 v = *(const float4*)&A[(size_t)gr * K + k0 + f];
      Xs[r][f] = v.x; Xs[r][f + 1] = v.y; Xs[r][f + 2] = v.z; Xs[r][f + 3] = v.w;
    }
    // stage W tile: 32xN floats
#pragma unroll
    for (int idx = tid; idx < (32 * N) / 4; idx += 256) {
      int fi = idx * 4; int wr = fi / N; int wc = fi % N;
      *(float4*)&Ws[wr][wc] = *(const float4*)&W[(size_t)(k0 + wr) * N + wc];
    }
    __syncthreads();
#pragma unroll
    for (int kk = 0; kk < 32; kk++) {
      float xv[4];
#pragma unroll
      for (int i = 0; i < 4; i++) xv[i] = Xs[ty * 4 + i][kk];
      float wv[CPT];
#pragma unroll
      for (int j = 0; j < CPT; j += 4) {
        float4 w4 = *(const float4*)&Ws[kk][tx * CPT + j];
        wv[j] = w4.x; wv[j + 1] = w4.y; wv[j + 2] = w4.z; wv[j + 3] = w4.w;
      }
#pragma unroll
      for (int i = 0; i < 4; i++)
#pragma unroll
        for (int j = 0; j < CPT; j++) acc[i][j] = fmaf(xv[i], wv[j], acc[i][j]);
    }
  }
#pragma unroll
  for (int i = 0; i < 4; i++) {
    int r = row0 + ty * 4 + i;
    if (r < M) {
      float d = dis[r];
#pragma unroll
      for (int j = 0; j < CPT; j += 4) {
        float4 o;
        o.x = d * acc[i][j]; o.y = d * acc[i][j + 1];
        o.z = d * acc[i][j + 2]; o.w = d * acc[i][j + 3];
        *(float4*)&out[(size_t)r * N + tx * CPT + j] = o;
      }
    }
  }
}

// ---------------- aggregation: out[v] = act(dis[v]*(g[v] + sum_u g[u]) + b) ----------------
// one wave per node; lane holds 2 (F=128) or 1 (F=64) features

template <int F, bool RELU>
__global__ __launch_bounds__(256) void k_agg(const float* __restrict__ g,
                                             const int* __restrict__ rowptr,
                                             const int* __restrict__ col,
                                             const float* __restrict__ dis,
                                             const float* __restrict__ bias,
                                             float* __restrict__ out, int n) {
  int lane = threadIdx.x & 63;
  int v = blockIdx.x * 4 + (threadIdx.x >> 6);
  if (v >= n) return;
  int p = rowptr[v], end = rowptr[v + 1];
  float dv = dis[v];
  if (F == 128) {
    float2 acc = *(const float2*)&g[(size_t)v * 128 + lane * 2];  // self term
    for (; p + 4 <= end; p += 4) {
      int u0 = col[p], u1 = col[p + 1], u2 = col[p + 2], u3 = col[p + 3];
      float2 t0 = *(const float2*)&g[(size_t)u0 * 128 + lane * 2];
      float2 t1 = *(const float2*)&g[(size_t)u1 * 128 + lane * 2];
      float2 t2 = *(const float2*)&g[(size_t)u2 * 128 + lane * 2];
      float2 t3 = *(const float2*)&g[(size_t)u3 * 128 + lane * 2];
      acc.x += t0.x + t1.x + t2.x + t3.x;
      acc.y += t0.y + t1.y + t2.y + t3.y;
    }
    for (; p < end; p++) {
      int u = col[p];
      float2 t = *(const float2*)&g[(size_t)u * 128 + lane * 2];
      acc.x += t.x; acc.y += t.y;
    }
    float ox = fmaf(dv, acc.x, bias[lane * 2]);
    float oy = fmaf(dv, acc.y, bias[lane * 2 + 1]);
    if (RELU) { ox = fmaxf(ox, 0.f); oy = fmaxf(oy, 0.f); }
    float2 o; o.x = ox; o.y = oy;
    *(float2*)&out[(size_t)v * 128 + lane * 2] = o;
  } else {
    float acc = g[(size_t)v * 64 + lane];
    for (; p + 4 <= end; p += 4) {
      int u0 = col[p], u1 = col[p + 1], u2 = col[p + 2], u3 = col[p + 3];
      acc += g[(size_t)u0 * 64 + lane] + g[(size_t)u1 * 64 + lane] +
             g[(size_t)u2 * 64 + lane] + g[(size_t)u3 * 64 + lane];
    }
    for (; p < end; p++) acc += g[(size_t)col[p] * 64 + lane];
    float o = fmaf(dv, acc, bias[lane]);
    if (RELU) o = fmaxf(o, 0.f);
    out[(size_t)v * 64 + lane] = o;
  }
}

// ---------------- launch ----------------

extern "C" void kernel_launch(void* const* d_in, const int* in_sizes, int n_in,
                              void* d_out, int out_size, void* d_ws, size_t ws_size,
                              hipStream_t stream) {
  const float* x  = (const float*)d_in[0];
  const int*   ei = (const int*)d_in[1];
  const float* W1 = (const float*)d_in[2];
  const float* b1 = (const float*)d_in[3];
  const float* W2 = (const float*)d_in[4];
  const float* b2 = (const float*)d_in[5];
  const float* W3 = (const float*)d_in[6];
  const float* b3 = (const float*)d_in[7];
  float* outp = (float*)d_out;

  const int N = in_sizes[0] / IN_DIM;   // 100000
  const int E = in_sizes[1] / 2;        // 3200000
  const int* src = ei;
  const int* dst = ei + E;

  char* w = (char*)d_ws;
  auto take = [&](size_t bytes) {
    char* r = w;
    w += (bytes + 255) & ~size_t(255);
    return r;
  };
  float* dis    = (float*)take((size_t)N * 4);
  int*   cnt    = (int*)take((size_t)N * 4);
  int*   rowptr = (int*)take((size_t)(N + 1) * 4);
  int*   pos    = (int*)take((size_t)N * 4);
  int*   bsum   = (int*)take(256 * 4);
  int*   col    = (int*)take((size_t)E * 4);
  float* bufA   = (float*)take((size_t)N * 128 * 4);
  float* bufB   = (float*)take((size_t)N * 128 * 4);

  const int nb = (N + 1023) / 1024;
  hipLaunchKernelGGL(k_zero, dim3((N + 255) / 256), dim3(256), 0, stream, cnt, N);
  hipLaunchKernelGGL(k_count, dim3((E + 255) / 256), dim3(256), 0, stream, dst, E, cnt);
  hipLaunchKernelGGL(k_bsum, dim3(nb), dim3(256), 0, stream, cnt, N, bsum);
  hipLaunchKernelGGL(k_bscan, dim3(1), dim3(256), 0, stream, bsum, nb);
  hipLaunchKernelGGL(k_scan_final, dim3(nb), dim3(256), 0, stream, cnt, N, bsum, rowptr, pos, dis, E);
  hipLaunchKernelGGL(k_fill, dim3((E + 255) / 256), dim3(256), 0, stream, src, dst, E, pos, col);

  const int gb = (N + 63) / 64;
  const int ab = (N + 3) / 4;
  // layer 1: g1 = dis*(x@W1) -> agg -> relu -> bufB
  hipLaunchKernelGGL((k_gemm<256, 128>), dim3(gb), dim3(256), 0, stream, x, W1, dis, bufA, N);
  hipLaunchKernelGGL((k_agg<128, true>), dim3(ab), dim3(256), 0, stream, bufA, rowptr, col, dis, b1, bufB, N);
  // layer 2
  hipLaunchKernelGGL((k_gemm<128, 128>), dim3(gb), dim3(256), 0, stream, bufB, W2, dis, bufA, N);
  hipLaunchKernelGGL((k_agg<128, true>), dim3(ab), dim3(256), 0, stream, bufA, rowptr, col, dis, b2, bufB, N);
  // layer 3 (no relu), output 64-dim straight to d_out
  hipLaunchKernelGGL((k_gemm<128, 64>), dim3(gb), dim3(256), 0, stream, bufB, W3, dis, bufA, N);
  hipLaunchKernelGGL((k_agg<64, false>), dim3(ab), dim3(256), 0, stream, bufA, rowptr, col, dis, b3, outp, N);
}

// Round 2
// 1211.370 us; speedup vs baseline: 1.0545x; 1.0545x over previous
//
#include <hip/hip_runtime.h>

constexpr int IN_DIM  = 256;
constexpr int HID_DIM = 128;
constexpr int OUT_DIM = 64;
constexpr int NPART   = 8;   // one node-partition per XCD

// ---------------- degree / CSR build ----------------

__global__ __launch_bounds__(256) void k_zero(int* __restrict__ p, int n) {
  int i = blockIdx.x * 256 + threadIdx.x;
  if (i < n) p[i] = 0;
}

// XCD-partitioned count: block b (XCD b%8) only counts dsts in its node range.
__global__ __launch_bounds__(256) void k_count_xcd(const int* __restrict__ dst, int E,
                                                   int* __restrict__ cnt, int npp, int chunks) {
  int part = blockIdx.x & (NPART - 1);
  int chunk = blockIdx.x / NPART;
  int lo = part * npp, hi = lo + npp;
  int per = (E + chunks - 1) / chunks;
  int e0 = chunk * per, e1 = min(e0 + per, E);
  for (int e = e0 + threadIdx.x; e < e1; e += 256) {
    int d = dst[e];
    if (d >= lo && d < hi) atomicAdd(&cnt[d], 1);
  }
}

// per-1024-element block sums
__global__ __launch_bounds__(256) void k_bsum(const int* __restrict__ cnt, int n,
                                              int* __restrict__ bsum) {
  __shared__ int sh[256];
  int t = threadIdx.x;
  int i0 = blockIdx.x * 1024 + t * 4;
  int s = 0;
#pragma unroll
  for (int j = 0; j < 4; j++) { int i = i0 + j; if (i < n) s += cnt[i]; }
  sh[t] = s; __syncthreads();
  for (int off = 128; off > 0; off >>= 1) {
    if (t < off) sh[t] += sh[t + off];
    __syncthreads();
  }
  if (t == 0) bsum[blockIdx.x] = sh[0];
}

// exclusive scan of block sums (nb <= 256), single block
__global__ void k_bscan(int* __restrict__ bsum, int nb) {
  __shared__ int sh[256];
  int t = threadIdx.x;
  if (t < nb) sh[t] = bsum[t];
  __syncthreads();
  if (t == 0) {
    int run = 0;
    for (int i = 0; i < nb; i++) { int v = sh[i]; sh[i] = run; run += v; }
  }
  __syncthreads();
  if (t < nb) bsum[t] = sh[t];
}

// final: rowptr (exclusive scan), cursor copy, dis = rsqrt(deg+1)
__global__ __launch_bounds__(256) void k_scan_final(
    const int* __restrict__ cnt, int n, const int* __restrict__ bbase,
    int* __restrict__ rowptr, int* __restrict__ pos, float* __restrict__ dis, int E) {
  __shared__ int sh[256];
  int t = threadIdx.x;
  int i0 = blockIdx.x * 1024 + t * 4;
  int c[4]; int s = 0;
#pragma unroll
  for (int j = 0; j < 4; j++) { int i = i0 + j; c[j] = (i < n) ? cnt[i] : 0; s += c[j]; }
  sh[t] = s; __syncthreads();
  for (int off = 1; off < 256; off <<= 1) {
    int add = (t >= off) ? sh[t - off] : 0;
    __syncthreads();
    sh[t] += add;
    __syncthreads();
  }
  int run = bbase[blockIdx.x] + sh[t] - s;  // exclusive prefix for this thread
#pragma unroll
  for (int j = 0; j < 4; j++) {
    int i = i0 + j;
    if (i < n) {
      rowptr[i] = run;
      pos[i] = run;
      dis[i] = rsqrtf((float)c[j] + 1.0f);  // +1 self loop
      run += c[j];
    }
  }
  if (blockIdx.x == 0 && t == 0) rowptr[n] = E;
}

// XCD-partitioned fill: each partition's col segment (~1.6 MB) is written only
// from blocks with blockIdx%8 == part (heuristically one XCD) -> lines stay in
// that XCD's L2 until full -> ~1x write amplification instead of ~16x.
__global__ __launch_bounds__(256) void k_fill_xcd(const int* __restrict__ src,
                                                  const int* __restrict__ dst, int E,
                                                  int* __restrict__ pos, int* __restrict__ col,
                                                  int npp, int chunks) {
  int part = blockIdx.x & (NPART - 1);
  int chunk = blockIdx.x / NPART;
  int lo = part * npp, hi = lo + npp;
  int per = (E + chunks - 1) / chunks;
  int e0 = chunk * per, e1 = min(e0 + per, E);
  for (int e = e0 + threadIdx.x; e < e1; e += 256) {
    int d = dst[e];
    if (d >= lo && d < hi) {
      int p = atomicAdd(&pos[d], 1);
      col[p] = src[e];
    }
  }
}

// ---------------- GEMM: out[r][c] = dis[r] * sum_k A[r][k]*W[k][c] ----------------
// BM=128, BK=32, block=256: 16 col-threads x 16 row-threads, 8 rows x N/16 cols each

template <int K, int N>
__global__ __launch_bounds__(256) void k_gemm(const float* __restrict__ A,
                                              const float* __restrict__ W,
                                              const float* __restrict__ dis,
                                              float* __restrict__ out, int M) {
  constexpr int CPT = N / 16;  // cols per thread: 8 (N=128) or 4 (N=64)
  __shared__ float Xs[128][33];  // +1 pad: conflict-free column reads
  __shared__ float Ws[32][N];
  const int tid = threadIdx.x;
  const int tx = tid & 15;
  const int ty = tid >> 4;
  const int row0 = blockIdx.x * 128;
  float acc[8][CPT];
#pragma unroll
  for (int i = 0; i < 8; i++)
#pragma unroll
    for (int j = 0; j < CPT; j++) acc[i][j] = 0.f;

  for (int k0 = 0; k0 < K; k0 += 32) {
    __syncthreads();
    // stage X tile: 128x32 floats (1024 float4 / 256 threads = 4 each)
#pragma unroll
    for (int idx = tid; idx < 1024; idx += 256) {
      int fi = idx * 4; int r = fi >> 5; int f = fi & 31;
      int gr = row0 + r; if (gr > M - 1) gr = M - 1;
      const float4 v = *(const float4*)&A[(size_t)gr * K + k0 + f];
      Xs[r][f] = v.x; Xs[r][f + 1] = v.y; Xs[r][f + 2] = v.z; Xs[r][f + 3] = v.w;
    }
    // stage W tile: 32xN floats
#pragma unroll
    for (int idx = tid; idx < (32 * N) / 4; idx += 256) {
      int fi = idx * 4; int wr = fi / N; int wc = fi % N;
      *(float4*)&Ws[wr][wc] = *(const float4*)&W[(size_t)(k0 + wr) * N + wc];
    }
    __syncthreads();
#pragma unroll
    for (int kk = 0; kk < 32; kk++) {
      float xv[8];
#pragma unroll
      for (int i = 0; i < 8; i++) xv[i] = Xs[ty * 8 + i][kk];
      float wv[CPT];
#pragma unroll
      for (int j = 0; j < CPT; j += 4) {
        float4 w4 = *(const float4*)&Ws[kk][tx * CPT + j];
        wv[j] = w4.x; wv[j + 1] = w4.y; wv[j + 2] = w4.z; wv[j + 3] = w4.w;
      }
#pragma unroll
      for (int i = 0; i < 8; i++)
#pragma unroll
        for (int j = 0; j < CPT; j++) acc[i][j] = fmaf(xv[i], wv[j], acc[i][j]);
    }
  }
#pragma unroll
  for (int i = 0; i < 8; i++) {
    int r = row0 + ty * 8 + i;
    if (r < M) {
      float d = dis[r];
#pragma unroll
      for (int j = 0; j < CPT; j += 4) {
        float4 o;
        o.x = d * acc[i][j]; o.y = d * acc[i][j + 1];
        o.z = d * acc[i][j + 2]; o.w = d * acc[i][j + 3];
        *(float4*)&out[(size_t)r * N + tx * CPT + j] = o;
      }
    }
  }
}

// ---------------- aggregation: out[v] = act(dis[v]*(g[v] + sum_u g[u]) + b) ----------------
// one wave per node; lane holds 2 (F=128) or 1 (F=64) features

template <int F, bool RELU>
__global__ __launch_bounds__(256) void k_agg(const float* __restrict__ g,
                                             const int* __restrict__ rowptr,
                                             const int* __restrict__ col,
                                             const float* __restrict__ dis,
                                             const float* __restrict__ bias,
                                             float* __restrict__ out, int n) {
  int lane = threadIdx.x & 63;
  int v = blockIdx.x * 4 + (threadIdx.x >> 6);
  if (v >= n) return;
  int p = rowptr[v], end = rowptr[v + 1];
  float dv = dis[v];
  if (F == 128) {
    float2 acc = *(const float2*)&g[(size_t)v * 128 + lane * 2];  // self term
    for (; p + 4 <= end; p += 4) {
      int u0 = col[p], u1 = col[p + 1], u2 = col[p + 2], u3 = col[p + 3];
      float2 t0 = *(const float2*)&g[(size_t)u0 * 128 + lane * 2];
      float2 t1 = *(const float2*)&g[(size_t)u1 * 128 + lane * 2];
      float2 t2 = *(const float2*)&g[(size_t)u2 * 128 + lane * 2];
      float2 t3 = *(const float2*)&g[(size_t)u3 * 128 + lane * 2];
      acc.x += t0.x + t1.x + t2.x + t3.x;
      acc.y += t0.y + t1.y + t2.y + t3.y;
    }
    for (; p < end; p++) {
      int u = col[p];
      float2 t = *(const float2*)&g[(size_t)u * 128 + lane * 2];
      acc.x += t.x; acc.y += t.y;
    }
    float ox = fmaf(dv, acc.x, bias[lane * 2]);
    float oy = fmaf(dv, acc.y, bias[lane * 2 + 1]);
    if (RELU) { ox = fmaxf(ox, 0.f); oy = fmaxf(oy, 0.f); }
    float2 o; o.x = ox; o.y = oy;
    *(float2*)&out[(size_t)v * 128 + lane * 2] = o;
  } else {
    float acc = g[(size_t)v * 64 + lane];
    for (; p + 4 <= end; p += 4) {
      int u0 = col[p], u1 = col[p + 1], u2 = col[p + 2], u3 = col[p + 3];
      acc += g[(size_t)u0 * 64 + lane] + g[(size_t)u1 * 64 + lane] +
             g[(size_t)u2 * 64 + lane] + g[(size_t)u3 * 64 + lane];
    }
    for (; p < end; p++) acc += g[(size_t)col[p] * 64 + lane];
    float o = fmaf(dv, acc, bias[lane]);
    if (RELU) o = fmaxf(o, 0.f);
    out[(size_t)v * 64 + lane] = o;
  }
}

// ---------------- launch ----------------

extern "C" void kernel_launch(void* const* d_in, const int* in_sizes, int n_in,
                              void* d_out, int out_size, void* d_ws, size_t ws_size,
                              hipStream_t stream) {
  const float* x  = (const float*)d_in[0];
  const int*   ei = (const int*)d_in[1];
  const float* W1 = (const float*)d_in[2];
  const float* b1 = (const float*)d_in[3];
  const float* W2 = (const float*)d_in[4];
  const float* b2 = (const float*)d_in[5];
  const float* W3 = (const float*)d_in[6];
  const float* b3 = (const float*)d_in[7];
  float* outp = (float*)d_out;

  const int N = in_sizes[0] / IN_DIM;   // 100000
  const int E = in_sizes[1] / 2;        // 3200000
  const int* src = ei;
  const int* dst = ei + E;

  char* w = (char*)d_ws;
  auto take = [&](size_t bytes) {
    char* r = w;
    w += (bytes + 255) & ~size_t(255);
    return r;
  };
  float* dis    = (float*)take((size_t)N * 4);
  int*   cnt    = (int*)take((size_t)N * 4);
  int*   rowptr = (int*)take((size_t)(N + 1) * 4);
  int*   pos    = (int*)take((size_t)N * 4);
  int*   bsum   = (int*)take(256 * 4);
  int*   col    = (int*)take((size_t)E * 4);
  float* bufA   = (float*)take((size_t)N * 128 * 4);
  float* bufB   = (float*)take((size_t)N * 128 * 4);

  const int nb = (N + 1023) / 1024;
  const int npp = (N + NPART - 1) / NPART;  // nodes per partition (12500)
  const int chunks = 256;                    // edge chunks per partition
  hipLaunchKernelGGL(k_zero, dim3((N + 255) / 256), dim3(256), 0, stream, cnt, N);
  hipLaunchKernelGGL(k_count_xcd, dim3(NPART * chunks), dim3(256), 0, stream, dst, E, cnt, npp, chunks);
  hipLaunchKernelGGL(k_bsum, dim3(nb), dim3(256), 0, stream, cnt, N, bsum);
  hipLaunchKernelGGL(k_bscan, dim3(1), dim3(256), 0, stream, bsum, nb);
  hipLaunchKernelGGL(k_scan_final, dim3(nb), dim3(256), 0, stream, cnt, N, bsum, rowptr, pos, dis, E);
  hipLaunchKernelGGL(k_fill_xcd, dim3(NPART * chunks), dim3(256), 0, stream, src, dst, E, pos, col, npp, chunks);

  const int gb = (N + 127) / 128;
  const int ab = (N + 3) / 4;
  // layer 1: g1 = dis*(x@W1) -> agg -> relu -> bufB
  hipLaunchKernelGGL((k_gemm<256, 128>), dim3(gb), dim3(256), 0, stream, x, W1, dis, bufA, N);
  hipLaunchKernelGGL((k_agg<128, true>), dim3(ab), dim3(256), 0, stream, bufA, rowptr, col, dis, b1, bufB, N);
  // layer 2
  hipLaunchKernelGGL((k_gemm<128, 128>), dim3(gb), dim3(256), 0, stream, bufB, W2, dis, bufA, N);
  hipLaunchKernelGGL((k_agg<128, true>), dim3(ab), dim3(256), 0, stream, bufA, rowptr, col, dis, b2, bufB, N);
  // layer 3 (no relu), output 64-dim straight to d_out
  hipLaunchKernelGGL((k_gemm<128, 64>), dim3(gb), dim3(256), 0, stream, bufB, W3, dis, bufA, N);
  hipLaunchKernelGGL((k_agg<64, false>), dim3(ab), dim3(256), 0, stream, bufA, rowptr, col, dis, b3, outp, N);
}

// Round 3
// 1032.889 us; speedup vs baseline: 1.2367x; 1.1728x over previous
//
#include <hip/hip_runtime.h>
#include <hip/hip_fp16.h>

constexpr int IN_DIM  = 256;
constexpr int HID_DIM = 128;
constexpr int OUT_DIM = 64;
constexpr int NPART   = 8;   // one node-partition per XCD

// ---------------- degree / CSR build ----------------

__global__ __launch_bounds__(256) void k_zero(int* __restrict__ p, int n) {
  int i = blockIdx.x * 256 + threadIdx.x;
  if (i < n) p[i] = 0;
}

// XCD-partitioned count: block b (XCD b%8) only counts dsts in its node range.
__global__ __launch_bounds__(256) void k_count_xcd(const int* __restrict__ dst, int E,
                                                   int* __restrict__ cnt, int npp, int chunks) {
  int part = blockIdx.x & (NPART - 1);
  int chunk = blockIdx.x / NPART;
  int lo = part * npp, hi = lo + npp;
  int per = (E + chunks - 1) / chunks;
  int e0 = chunk * per, e1 = min(e0 + per, E);
  for (int e = e0 + threadIdx.x; e < e1; e += 256) {
    int d = dst[e];
    if (d >= lo && d < hi) atomicAdd(&cnt[d], 1);
  }
}

// per-1024-element block sums
__global__ __launch_bounds__(256) void k_bsum(const int* __restrict__ cnt, int n,
                                              int* __restrict__ bsum) {
  __shared__ int sh[256];
  int t = threadIdx.x;
  int i0 = blockIdx.x * 1024 + t * 4;
  int s = 0;
#pragma unroll
  for (int j = 0; j < 4; j++) { int i = i0 + j; if (i < n) s += cnt[i]; }
  sh[t] = s; __syncthreads();
  for (int off = 128; off > 0; off >>= 1) {
    if (t < off) sh[t] += sh[t + off];
    __syncthreads();
  }
  if (t == 0) bsum[blockIdx.x] = sh[0];
}

// exclusive scan of block sums (nb <= 256), single block
__global__ void k_bscan(int* __restrict__ bsum, int nb) {
  __shared__ int sh[256];
  int t = threadIdx.x;
  if (t < nb) sh[t] = bsum[t];
  __syncthreads();
  if (t == 0) {
    int run = 0;
    for (int i = 0; i < nb; i++) { int v = sh[i]; sh[i] = run; run += v; }
  }
  __syncthreads();
  if (t < nb) bsum[t] = sh[t];
}

// final: rowptr (exclusive scan), cursor copy, dis = rsqrt(deg+1)
__global__ __launch_bounds__(256) void k_scan_final(
    const int* __restrict__ cnt, int n, const int* __restrict__ bbase,
    int* __restrict__ rowptr, int* __restrict__ pos, float* __restrict__ dis, int E) {
  __shared__ int sh[256];
  int t = threadIdx.x;
  int i0 = blockIdx.x * 1024 + t * 4;
  int c[4]; int s = 0;
#pragma unroll
  for (int j = 0; j < 4; j++) { int i = i0 + j; c[j] = (i < n) ? cnt[i] : 0; s += c[j]; }
  sh[t] = s; __syncthreads();
  for (int off = 1; off < 256; off <<= 1) {
    int add = (t >= off) ? sh[t - off] : 0;
    __syncthreads();
    sh[t] += add;
    __syncthreads();
  }
  int run = bbase[blockIdx.x] + sh[t] - s;  // exclusive prefix for this thread
#pragma unroll
  for (int j = 0; j < 4; j++) {
    int i = i0 + j;
    if (i < n) {
      rowptr[i] = run;
      pos[i] = run;
      dis[i] = rsqrtf((float)c[j] + 1.0f);  // +1 self loop
      run += c[j];
    }
  }
  if (blockIdx.x == 0 && t == 0) rowptr[n] = E;
}

// XCD-partitioned fill: each partition's col segment (~1.6 MB) is written only
// from blocks with blockIdx%8 == part (heuristically one XCD) -> ~1x write amp.
__global__ __launch_bounds__(256) void k_fill_xcd(const int* __restrict__ src,
                                                  const int* __restrict__ dst, int E,
                                                  int* __restrict__ pos, int* __restrict__ col,
                                                  int npp, int chunks) {
  int part = blockIdx.x & (NPART - 1);
  int chunk = blockIdx.x / NPART;
  int lo = part * npp, hi = lo + npp;
  int per = (E + chunks - 1) / chunks;
  int e0 = chunk * per, e1 = min(e0 + per, E);
  for (int e = e0 + threadIdx.x; e < e1; e += 256) {
    int d = dst[e];
    if (d >= lo && d < hi) {
      int p = atomicAdd(&pos[d], 1);
      col[p] = src[e];
    }
  }
}

// ---------------- GEMM: out[r][c] = (half) dis[r] * sum_k A[r][k]*W[k][c] ----------------
// BM=128, BK=32, block=256: 16 col-threads x 16 row-threads, 8 rows x N/16 cols each.
// fp32 compute, fp16 output (output only feeds the gather).

template <int K, int N>
__global__ __launch_bounds__(256) void k_gemm_h(const float* __restrict__ A,
                                                const float* __restrict__ W,
                                                const float* __restrict__ dis,
                                                __half* __restrict__ out, int M) {
  constexpr int CPT = N / 16;  // cols per thread: 8 (N=128) or 4 (N=64)
  __shared__ float Xs[128][33];  // +1 pad: conflict-free column reads
  __shared__ float Ws[32][N];
  const int tid = threadIdx.x;
  const int tx = tid & 15;
  const int ty = tid >> 4;
  const int row0 = blockIdx.x * 128;
  float acc[8][CPT];
#pragma unroll
  for (int i = 0; i < 8; i++)
#pragma unroll
    for (int j = 0; j < CPT; j++) acc[i][j] = 0.f;

  for (int k0 = 0; k0 < K; k0 += 32) {
    __syncthreads();
    // stage X tile: 128x32 floats (1024 float4 / 256 threads = 4 each)
#pragma unroll
    for (int idx = tid; idx < 1024; idx += 256) {
      int fi = idx * 4; int r = fi >> 5; int f = fi & 31;
      int gr = row0 + r; if (gr > M - 1) gr = M - 1;
      const float4 v = *(const float4*)&A[(size_t)gr * K + k0 + f];
      Xs[r][f] = v.x; Xs[r][f + 1] = v.y; Xs[r][f + 2] = v.z; Xs[r][f + 3] = v.w;
    }
    // stage W tile: 32xN floats
#pragma unroll
    for (int idx = tid; idx < (32 * N) / 4; idx += 256) {
      int fi = idx * 4; int wr = fi / N; int wc = fi % N;
      *(float4*)&Ws[wr][wc] = *(const float4*)&W[(size_t)(k0 + wr) * N + wc];
    }
    __syncthreads();
#pragma unroll
    for (int kk = 0; kk < 32; kk++) {
      float xv[8];
#pragma unroll
      for (int i = 0; i < 8; i++) xv[i] = Xs[ty * 8 + i][kk];
      float wv[CPT];
#pragma unroll
      for (int j = 0; j < CPT; j += 4) {
        float4 w4 = *(const float4*)&Ws[kk][tx * CPT + j];
        wv[j] = w4.x; wv[j + 1] = w4.y; wv[j + 2] = w4.z; wv[j + 3] = w4.w;
      }
#pragma unroll
      for (int i = 0; i < 8; i++)
#pragma unroll
        for (int j = 0; j < CPT; j++) acc[i][j] = fmaf(xv[i], wv[j], acc[i][j]);
    }
  }
#pragma unroll
  for (int i = 0; i < 8; i++) {
    int r = row0 + ty * 8 + i;
    if (r < M) {
      float d = dis[r];
      __half tmp[CPT];
#pragma unroll
      for (int j = 0; j < CPT; j++) tmp[j] = __float2half_rn(d * acc[i][j]);
      if (CPT == 8) {
        *(float4*)&out[(size_t)r * N + tx * CPT] = *(const float4*)tmp;
      } else {
        *(float2*)&out[(size_t)r * N + tx * CPT] = *(const float2*)tmp;
      }
    }
  }
}

// ---------------- aggregation: out[v] = act(dv*(g[v] + sum_u g[u]) + b) ----------------
// one wave per node; g stored fp16 (halves gather bytes), fp32 accumulate.

template <int F, bool RELU>
__global__ __launch_bounds__(256) void k_agg(const __half* __restrict__ g,
                                             const int* __restrict__ rowptr,
                                             const int* __restrict__ col,
                                             const float* __restrict__ dis,
                                             const float* __restrict__ bias,
                                             float* __restrict__ out, int n) {
  int lane = threadIdx.x & 63;
  int v = blockIdx.x * 4 + (threadIdx.x >> 6);
  if (v >= n) return;
  int p = rowptr[v], end = rowptr[v + 1];
  float dv = dis[v];
  if (F == 128) {
    float2 f0 = __half22float2(*(const __half2*)&g[(size_t)v * 128 + lane * 2]);
    float ax = f0.x, ay = f0.y;  // self term
    for (; p + 8 <= end; p += 8) {
      int u[8];
#pragma unroll
      for (int j = 0; j < 8; j++) u[j] = __builtin_nontemporal_load(&col[p + j]);
      __half2 t[8];
#pragma unroll
      for (int j = 0; j < 8; j++) t[j] = *(const __half2*)&g[(size_t)u[j] * 128 + lane * 2];
#pragma unroll
      for (int j = 0; j < 8; j++) {
        float2 f = __half22float2(t[j]);
        ax += f.x; ay += f.y;
      }
    }
    for (; p < end; p++) {
      int u = __builtin_nontemporal_load(&col[p]);
      float2 f = __half22float2(*(const __half2*)&g[(size_t)u * 128 + lane * 2]);
      ax += f.x; ay += f.y;
    }
    float ox = fmaf(dv, ax, bias[lane * 2]);
    float oy = fmaf(dv, ay, bias[lane * 2 + 1]);
    if (RELU) { ox = fmaxf(ox, 0.f); oy = fmaxf(oy, 0.f); }
    float2 o; o.x = ox; o.y = oy;
    *(float2*)&out[(size_t)v * 128 + lane * 2] = o;
  } else {
    float acc = __half2float(g[(size_t)v * 64 + lane]);
    for (; p + 8 <= end; p += 8) {
      int u[8];
#pragma unroll
      for (int j = 0; j < 8; j++) u[j] = __builtin_nontemporal_load(&col[p + j]);
      __half t[8];
#pragma unroll
      for (int j = 0; j < 8; j++) t[j] = g[(size_t)u[j] * 64 + lane];
#pragma unroll
      for (int j = 0; j < 8; j++) acc += __half2float(t[j]);
    }
    for (; p < end; p++) {
      int u = __builtin_nontemporal_load(&col[p]);
      acc += __half2float(g[(size_t)u * 64 + lane]);
    }
    float o = fmaf(dv, acc, bias[lane]);
    if (RELU) o = fmaxf(o, 0.f);
    out[(size_t)v * 64 + lane] = o;
  }
}

// ---------------- launch ----------------

extern "C" void kernel_launch(void* const* d_in, const int* in_sizes, int n_in,
                              void* d_out, int out_size, void* d_ws, size_t ws_size,
                              hipStream_t stream) {
  const float* x  = (const float*)d_in[0];
  const int*   ei = (const int*)d_in[1];
  const float* W1 = (const float*)d_in[2];
  const float* b1 = (const float*)d_in[3];
  const float* W2 = (const float*)d_in[4];
  const float* b2 = (const float*)d_in[5];
  const float* W3 = (const float*)d_in[6];
  const float* b3 = (const float*)d_in[7];
  float* outp = (float*)d_out;

  const int N = in_sizes[0] / IN_DIM;   // 100000
  const int E = in_sizes[1] / 2;        // 3200000
  const int* src = ei;
  const int* dst = ei + E;

  char* w = (char*)d_ws;
  auto take = [&](size_t bytes) {
    char* r = w;
    w += (bytes + 255) & ~size_t(255);
    return r;
  };
  float*  dis    = (float*)take((size_t)N * 4);
  int*    cnt    = (int*)take((size_t)N * 4);
  int*    rowptr = (int*)take((size_t)(N + 1) * 4);
  int*    pos    = (int*)take((size_t)N * 4);
  int*    bsum   = (int*)take(256 * 4);
  int*    col    = (int*)take((size_t)E * 4);
  __half* gbuf   = (__half*)take((size_t)N * 128 * 2);  // fp16 gather buffer
  float*  bufB   = (float*)take((size_t)N * 128 * 4);   // fp32 agg output

  const int nb = (N + 1023) / 1024;
  const int npp = (N + NPART - 1) / NPART;  // nodes per partition (12500)
  const int chunks = 256;                    // edge chunks per partition
  hipLaunchKernelGGL(k_zero, dim3((N + 255) / 256), dim3(256), 0, stream, cnt, N);
  hipLaunchKernelGGL(k_count_xcd, dim3(NPART * chunks), dim3(256), 0, stream, dst, E, cnt, npp, chunks);
  hipLaunchKernelGGL(k_bsum, dim3(nb), dim3(256), 0, stream, cnt, N, bsum);
  hipLaunchKernelGGL(k_bscan, dim3(1), dim3(256), 0, stream, bsum, nb);
  hipLaunchKernelGGL(k_scan_final, dim3(nb), dim3(256), 0, stream, cnt, N, bsum, rowptr, pos, dis, E);
  hipLaunchKernelGGL(k_fill_xcd, dim3(NPART * chunks), dim3(256), 0, stream, src, dst, E, pos, col, npp, chunks);

  const int gb = (N + 127) / 128;
  const int ab = (N + 3) / 4;
  // layer 1: g1 = fp16(dis*(x@W1)) -> agg -> relu -> bufB (fp32)
  hipLaunchKernelGGL((k_gemm_h<256, 128>), dim3(gb), dim3(256), 0, stream, x, W1, dis, gbuf, N);
  hipLaunchKernelGGL((k_agg<128, true>), dim3(ab), dim3(256), 0, stream, gbuf, rowptr, col, dis, b1, bufB, N);
  // layer 2
  hipLaunchKernelGGL((k_gemm_h<128, 128>), dim3(gb), dim3(256), 0, stream, bufB, W2, dis, gbuf, N);
  hipLaunchKernelGGL((k_agg<128, true>), dim3(ab), dim3(256), 0, stream, gbuf, rowptr, col, dis, b2, bufB, N);
  // layer 3 (no relu), output 64-dim straight to d_out (fp32)
  hipLaunchKernelGGL((k_gemm_h<128, 64>), dim3(gb), dim3(256), 0, stream, bufB, W3, dis, gbuf, N);
  hipLaunchKernelGGL((k_agg<64, false>), dim3(ab), dim3(256), 0, stream, gbuf, rowptr, col, dis, b3, outp, N);
}

// Round 4
// 1029.750 us; speedup vs baseline: 1.2405x; 1.0030x over previous
//
#include <hip/hip_runtime.h>
#include <hip/hip_fp16.h>

constexpr int IN_DIM  = 256;
constexpr int HID_DIM = 128;
constexpr int OUT_DIM = 64;
constexpr int NPART   = 8;   // one node-partition per XCD

// ---------------- degree / CSR build ----------------

__global__ __launch_bounds__(256) void k_zero(int* __restrict__ p, int n) {
  int i = blockIdx.x * 256 + threadIdx.x;
  if (i < n) p[i] = 0;
}

// XCD-partitioned count: block b (XCD b%8) only counts dsts in its node range.
// nt loads: don't let the dst stream evict cnt lines from L2.
__global__ __launch_bounds__(256) void k_count_xcd(const int* __restrict__ dst, int E,
                                                   int* __restrict__ cnt, int npp, int chunks) {
  int part = blockIdx.x & (NPART - 1);
  int chunk = blockIdx.x / NPART;
  int lo = part * npp, hi = lo + npp;
  int per = (E + chunks - 1) / chunks;
  int e0 = chunk * per, e1 = min(e0 + per, E);
  for (int e = e0 + threadIdx.x; e < e1; e += 256) {
    int d = __builtin_nontemporal_load(&dst[e]);
    if (d >= lo && d < hi) atomicAdd(&cnt[d], 1);
  }
}

// per-1024-element block sums
__global__ __launch_bounds__(256) void k_bsum(const int* __restrict__ cnt, int n,
                                              int* __restrict__ bsum) {
  __shared__ int sh[256];
  int t = threadIdx.x;
  int i0 = blockIdx.x * 1024 + t * 4;
  int s = 0;
#pragma unroll
  for (int j = 0; j < 4; j++) { int i = i0 + j; if (i < n) s += cnt[i]; }
  sh[t] = s; __syncthreads();
  for (int off = 128; off > 0; off >>= 1) {
    if (t < off) sh[t] += sh[t + off];
    __syncthreads();
  }
  if (t == 0) bsum[blockIdx.x] = sh[0];
}

// exclusive scan of block sums (nb <= 256), single block
__global__ void k_bscan(int* __restrict__ bsum, int nb) {
  __shared__ int sh[256];
  int t = threadIdx.x;
  if (t < nb) sh[t] = bsum[t];
  __syncthreads();
  if (t == 0) {
    int run = 0;
    for (int i = 0; i < nb; i++) { int v = sh[i]; sh[i] = run; run += v; }
  }
  __syncthreads();
  if (t < nb) bsum[t] = sh[t];
}

// final: rowptr (exclusive scan), cursor copy, dis = rsqrt(deg+1)
__global__ __launch_bounds__(256) void k_scan_final(
    const int* __restrict__ cnt, int n, const int* __restrict__ bbase,
    int* __restrict__ rowptr, int* __restrict__ pos, float* __restrict__ dis, int E) {
  __shared__ int sh[256];
  int t = threadIdx.x;
  int i0 = blockIdx.x * 1024 + t * 4;
  int c[4]; int s = 0;
#pragma unroll
  for (int j = 0; j < 4; j++) { int i = i0 + j; c[j] = (i < n) ? cnt[i] : 0; s += c[j]; }
  sh[t] = s; __syncthreads();
  for (int off = 1; off < 256; off <<= 1) {
    int add = (t >= off) ? sh[t - off] : 0;
    __syncthreads();
    sh[t] += add;
    __syncthreads();
  }
  int run = bbase[blockIdx.x] + sh[t] - s;  // exclusive prefix for this thread
#pragma unroll
  for (int j = 0; j < 4; j++) {
    int i = i0 + j;
    if (i < n) {
      rowptr[i] = run;
      pos[i] = run;
      dis[i] = rsqrtf((float)c[j] + 1.0f);  // +1 self loop
      run += c[j];
    }
  }
  if (blockIdx.x == 0 && t == 0) rowptr[n] = E;
}

// XCD-partitioned fill. nt loads on the dst/src streams so the partition's col
// segment (~1.6 MB) and pos cursors stay L2-resident -> ~1x write amplification.
__global__ __launch_bounds__(256) void k_fill_xcd(const int* __restrict__ src,
                                                  const int* __restrict__ dst, int E,
                                                  int* __restrict__ pos, int* __restrict__ col,
                                                  int npp, int chunks) {
  int part = blockIdx.x & (NPART - 1);
  int chunk = blockIdx.x / NPART;
  int lo = part * npp, hi = lo + npp;
  int per = (E + chunks - 1) / chunks;
  int e0 = chunk * per, e1 = min(e0 + per, E);
  for (int e = e0 + threadIdx.x; e < e1; e += 256) {
    int d = __builtin_nontemporal_load(&dst[e]);
    if (d >= lo && d < hi) {
      int s = __builtin_nontemporal_load(&src[e]);
      int p = atomicAdd(&pos[d], 1);
      col[p] = s;
    }
  }
}

// ---------------- GEMM: out[r][c] = (half) dis[r] * sum_k A[r][k]*W[k][c] ----------------
// BM=128, BK=32, block=256: 16 col-threads x 16 row-threads, 8 rows x N/16 cols each.
// fp32 compute, fp16 output (output only feeds the gather).

template <int K, int N>
__global__ __launch_bounds__(256) void k_gemm_h(const float* __restrict__ A,
                                                const float* __restrict__ W,
                                                const float* __restrict__ dis,
                                                __half* __restrict__ out, int M) {
  constexpr int CPT = N / 16;  // cols per thread: 8 (N=128) or 4 (N=64)
  __shared__ float Xs[128][33];  // +1 pad: conflict-free column reads
  __shared__ float Ws[32][N];
  const int tid = threadIdx.x;
  const int tx = tid & 15;
  const int ty = tid >> 4;
  const int row0 = blockIdx.x * 128;
  float acc[8][CPT];
#pragma unroll
  for (int i = 0; i < 8; i++)
#pragma unroll
    for (int j = 0; j < CPT; j++) acc[i][j] = 0.f;

  for (int k0 = 0; k0 < K; k0 += 32) {
    __syncthreads();
    // stage X tile: 128x32 floats (1024 float4 / 256 threads = 4 each)
#pragma unroll
    for (int idx = tid; idx < 1024; idx += 256) {
      int fi = idx * 4; int r = fi >> 5; int f = fi & 31;
      int gr = row0 + r; if (gr > M - 1) gr = M - 1;
      const float4 v = *(const float4*)&A[(size_t)gr * K + k0 + f];
      Xs[r][f] = v.x; Xs[r][f + 1] = v.y; Xs[r][f + 2] = v.z; Xs[r][f + 3] = v.w;
    }
    // stage W tile: 32xN floats
#pragma unroll
    for (int idx = tid; idx < (32 * N) / 4; idx += 256) {
      int fi = idx * 4; int wr = fi / N; int wc = fi % N;
      *(float4*)&Ws[wr][wc] = *(const float4*)&W[(size_t)(k0 + wr) * N + wc];
    }
    __syncthreads();
#pragma unroll
    for (int kk = 0; kk < 32; kk++) {
      float xv[8];
#pragma unroll
      for (int i = 0; i < 8; i++) xv[i] = Xs[ty * 8 + i][kk];
      float wv[CPT];
#pragma unroll
      for (int j = 0; j < CPT; j += 4) {
        float4 w4 = *(const float4*)&Ws[kk][tx * CPT + j];
        wv[j] = w4.x; wv[j + 1] = w4.y; wv[j + 2] = w4.z; wv[j + 3] = w4.w;
      }
#pragma unroll
      for (int i = 0; i < 8; i++)
#pragma unroll
        for (int j = 0; j < CPT; j++) acc[i][j] = fmaf(xv[i], wv[j], acc[i][j]);
    }
  }
#pragma unroll
  for (int i = 0; i < 8; i++) {
    int r = row0 + ty * 8 + i;
    if (r < M) {
      float d = dis[r];
      __half tmp[CPT];
#pragma unroll
      for (int j = 0; j < CPT; j++) tmp[j] = __float2half_rn(d * acc[i][j]);
      if (CPT == 8) {
        *(float4*)&out[(size_t)r * N + tx * CPT] = *(const float4*)tmp;
      } else {
        *(float2*)&out[(size_t)r * N + tx * CPT] = *(const float2*)tmp;
      }
    }
  }
}

// ---------------- aggregation: out[v] = act(dv*(g[v] + sum_u g[u]) + b) ----------------
// one wave per node; g stored fp16 (halves gather bytes), fp32 accumulate.

template <int F, bool RELU>
__global__ __launch_bounds__(256) void k_agg(const __half* __restrict__ g,
                                             const int* __restrict__ rowptr,
                                             const int* __restrict__ col,
                                             const float* __restrict__ dis,
                                             const float* __restrict__ bias,
                                             float* __restrict__ out, int n) {
  int lane = threadIdx.x & 63;
  int v = blockIdx.x * 4 + (threadIdx.x >> 6);
  if (v >= n) return;
  int p = rowptr[v], end = rowptr[v + 1];
  float dv = dis[v];
  if (F == 128) {
    float2 f0 = __half22float2(*(const __half2*)&g[(size_t)v * 128 + lane * 2]);
    float ax = f0.x, ay = f0.y;  // self term
    for (; p + 8 <= end; p += 8) {
      int u[8];
#pragma unroll
      for (int j = 0; j < 8; j++) u[j] = __builtin_nontemporal_load(&col[p + j]);
      __half2 t[8];
#pragma unroll
      for (int j = 0; j < 8; j++) t[j] = *(const __half2*)&g[(size_t)u[j] * 128 + lane * 2];
#pragma unroll
      for (int j = 0; j < 8; j++) {
        float2 f = __half22float2(t[j]);
        ax += f.x; ay += f.y;
      }
    }
    for (; p < end; p++) {
      int u = __builtin_nontemporal_load(&col[p]);
      float2 f = __half22float2(*(const __half2*)&g[(size_t)u * 128 + lane * 2]);
      ax += f.x; ay += f.y;
    }
    float ox = fmaf(dv, ax, bias[lane * 2]);
    float oy = fmaf(dv, ay, bias[lane * 2 + 1]);
    if (RELU) { ox = fmaxf(ox, 0.f); oy = fmaxf(oy, 0.f); }
    float2 o; o.x = ox; o.y = oy;
    *(float2*)&out[(size_t)v * 128 + lane * 2] = o;
  } else {
    float acc = __half2float(g[(size_t)v * 64 + lane]);
    for (; p + 8 <= end; p += 8) {
      int u[8];
#pragma unroll
      for (int j = 0; j < 8; j++) u[j] = __builtin_nontemporal_load(&col[p + j]);
      __half t[8];
#pragma unroll
      for (int j = 0; j < 8; j++) t[j] = g[(size_t)u[j] * 64 + lane];
#pragma unroll
      for (int j = 0; j < 8; j++) acc += __half2float(t[j]);
    }
    for (; p < end; p++) {
      int u = __builtin_nontemporal_load(&col[p]);
      acc += __half2float(g[(size_t)u * 64 + lane]);
    }
    float o = fmaf(dv, acc, bias[lane]);
    if (RELU) o = fmaxf(o, 0.f);
    out[(size_t)v * 64 + lane] = o;
  }
}

// ---------------- launch ----------------

extern "C" void kernel_launch(void* const* d_in, const int* in_sizes, int n_in,
                              void* d_out, int out_size, void* d_ws, size_t ws_size,
                              hipStream_t stream) {
  const float* x  = (const float*)d_in[0];
  const int*   ei = (const int*)d_in[1];
  const float* W1 = (const float*)d_in[2];
  const float* b1 = (const float*)d_in[3];
  const float* W2 = (const float*)d_in[4];
  const float* b2 = (const float*)d_in[5];
  const float* W3 = (const float*)d_in[6];
  const float* b3 = (const float*)d_in[7];
  float* outp = (float*)d_out;

  const int N = in_sizes[0] / IN_DIM;   // 100000
  const int E = in_sizes[1] / 2;        // 3200000
  const int* src = ei;
  const int* dst = ei + E;

  char* w = (char*)d_ws;
  auto take = [&](size_t bytes) {
    char* r = w;
    w += (bytes + 255) & ~size_t(255);
    return r;
  };
  float*  dis    = (float*)take((size_t)N * 4);
  int*    cnt    = (int*)take((size_t)N * 4);
  int*    rowptr = (int*)take((size_t)(N + 1) * 4);
  int*    pos    = (int*)take((size_t)N * 4);
  int*    bsum   = (int*)take(256 * 4);
  int*    col    = (int*)take((size_t)E * 4);
  __half* gbuf   = (__half*)take((size_t)N * 128 * 2);  // fp16 gather buffer
  float*  bufB   = (float*)take((size_t)N * 128 * 4);   // fp32 agg output

  const int nb = (N + 1023) / 1024;
  const int npp = (N + NPART - 1) / NPART;  // nodes per partition (12500)
  const int chunks = 256;                    // edge chunks per partition
  hipLaunchKernelGGL(k_zero, dim3((N + 255) / 256), dim3(256), 0, stream, cnt, N);
  hipLaunchKernelGGL(k_count_xcd, dim3(NPART * chunks), dim3(256), 0, stream, dst, E, cnt, npp, chunks);
  hipLaunchKernelGGL(k_bsum, dim3(nb), dim3(256), 0, stream, cnt, N, bsum);
  hipLaunchKernelGGL(k_bscan, dim3(1), dim3(256), 0, stream, bsum, nb);
  hipLaunchKernelGGL(k_scan_final, dim3(nb), dim3(256), 0, stream, cnt, N, bsum, rowptr, pos, dis, E);
  hipLaunchKernelGGL(k_fill_xcd, dim3(NPART * chunks), dim3(256), 0, stream, src, dst, E, pos, col, npp, chunks);

  const int gb = (N + 127) / 128;
  const int ab = (N + 3) / 4;
  // layer 1: g1 = fp16(dis*(x@W1)) -> agg -> relu -> bufB (fp32)
  hipLaunchKernelGGL((k_gemm_h<256, 128>), dim3(gb), dim3(256), 0, stream, x, W1, dis, gbuf, N);
  hipLaunchKernelGGL((k_agg<128, true>), dim3(ab), dim3(256), 0, stream, gbuf, rowptr, col, dis, b1, bufB, N);
  // layer 2
  hipLaunchKernelGGL((k_gemm_h<128, 128>), dim3(gb), dim3(256), 0, stream, bufB, W2, dis, gbuf, N);
  hipLaunchKernelGGL((k_agg<128, true>), dim3(ab), dim3(256), 0, stream, gbuf, rowptr, col, dis, b2, bufB, N);
  // layer 3 (no relu), output 64-dim straight to d_out (fp32)
  hipLaunchKernelGGL((k_gemm_h<128, 64>), dim3(gb), dim3(256), 0, stream, bufB, W3, dis, gbuf, N);
  hipLaunchKernelGGL((k_agg<64, false>), dim3(ab), dim3(256), 0, stream, gbuf, rowptr, col, dis, b3, outp, N);
}